// Round 3
// baseline (486.269 us; speedup 1.0000x reference)
//
#include <hip/hip_runtime.h>

#define NP 1024
#define EMB 1024
#define NH 16
#define HD 64
#define SCALE 0.125f

typedef unsigned short u16;
typedef unsigned int u32;
typedef __bf16 bf16x8 __attribute__((ext_vector_type(8)));
typedef float f32x4 __attribute__((ext_vector_type(4)));

__device__ __forceinline__ u16 f2bf(float f) {
  u32 u = __builtin_bit_cast(u32, f);
  return (u16)((u + 0x7fffu + ((u >> 16) & 1u)) >> 16);
}

__device__ __forceinline__ f32x4 zero4() {
  f32x4 z; z[0] = 0.f; z[1] = 0.f; z[2] = 0.f; z[3] = 0.f; return z;
}

__device__ __forceinline__ void async16(const u16* g, u16* l) {
  __builtin_amdgcn_global_load_lds(
      (const __attribute__((address_space(1))) u32*)g,
      (__attribute__((address_space(3))) u32*)l, 16, 0, 0);
}

// ---------------- fp32 -> bf16 conversion (x, w_in, w_out fused) ----------------
__global__ __launch_bounds__(256) void k_convert3(const float* __restrict__ x,
                                                  const float* __restrict__ w_in,
                                                  const float* __restrict__ w_out,
                                                  u16* __restrict__ xb,
                                                  u16* __restrict__ winb,
                                                  u16* __restrict__ woutb) {
  const int b = blockIdx.x;
  const float* src;
  u16* dst;
  int i;
  if (b < 4096)      { src = x;     dst = xb;    i = b * 256 + threadIdx.x; }
  else if (b < 7168) { src = w_in;  dst = winb;  i = (b - 4096) * 256 + threadIdx.x; }
  else               { src = w_out; dst = woutb; i = (b - 7168) * 256 + threadIdx.x; }
  float4 v = reinterpret_cast<const float4*>(src)[i];
  uint2 o;
  o.x = (u32)f2bf(v.x) | ((u32)f2bf(v.y) << 16);
  o.y = (u32)f2bf(v.z) | ((u32)f2bf(v.w) << 16);
  reinterpret_cast<uint2*>(dst)[i] = o;
}

// ---------------- 128x128 bf16 GEMM core (C = A * B^T), m97 structure ----------------
// A: [M][K] bf16 row-major, B: [N][K] bf16 row-major. BK=32, 4 waves, 4x4 frags/wave.
__device__ __forceinline__ void gemm_bt_core(const u16* __restrict__ Ag,
                                             const u16* __restrict__ Bg,
                                             int K, int mbase, int nbase,
                                             u16* Ash, u16* Bsh, f32x4 acc[4][4]) {
  const int tid = threadIdx.x;
  const int lane = tid & 63;
  const int wid = tid >> 6;
  const int uwid = __builtin_amdgcn_readfirstlane(wid);
  const int wr = wid >> 1, wc = wid & 1;

#pragma unroll
  for (int i = 0; i < 4; ++i)
#pragma unroll
    for (int j = 0; j < 4; ++j) acc[i][j] = zero4();

  // staging: wave uwid owns LDS rows [uwid*32, uwid*32+32) via two 1KB chunks.
  const int r0 = uwid * 32 + (lane >> 2);
  const u16* a0 = Ag + (size_t)(mbase + r0) * K + (lane & 3) * 8;
  const u16* a1 = a0 + (size_t)16 * K;
  const u16* b0 = Bg + (size_t)(nbase + r0) * K + (lane & 3) * 8;
  const u16* b1 = b0 + (size_t)16 * K;
  u16* la0 = Ash + uwid * 1024;
  u16* la1 = la0 + 512;
  u16* lb0 = Bsh + uwid * 1024;
  u16* lb1 = lb0 + 512;

  for (int k0 = 0; k0 < K; k0 += 32) {
    async16(a0 + k0, la0);
    async16(a1 + k0, la1);
    async16(b0 + k0, lb0);
    async16(b1 + k0, lb1);
    __syncthreads();
    bf16x8 af[4], bfr[4];
#pragma unroll
    for (int mi = 0; mi < 4; ++mi)
      af[mi] = *reinterpret_cast<const bf16x8*>(
          Ash + (wr * 64 + mi * 16 + (lane & 15)) * 32 + (lane >> 4) * 8);
#pragma unroll
    for (int ni = 0; ni < 4; ++ni)
      bfr[ni] = *reinterpret_cast<const bf16x8*>(
          Bsh + (wc * 64 + ni * 16 + (lane & 15)) * 32 + (lane >> 4) * 8);
#pragma unroll
    for (int mi = 0; mi < 4; ++mi)
#pragma unroll
      for (int ni = 0; ni < 4; ++ni)
        acc[mi][ni] = __builtin_amdgcn_mfma_f32_16x16x32_bf16(af[mi], bfr[ni],
                                                              acc[mi][ni], 0, 0, 0);
    __syncthreads();
  }
}

// ---------------- QKV projection ----------------
// C[m][n] = sum_k x[m][k]*w_in[n][k] + b_in[n]; scatter into Q,K [BH][NP][HD]
// and V^T [BH][HD][NP], all bf16.
__global__ __launch_bounds__(256) void k_qkv(const u16* __restrict__ xb,
                                             const u16* __restrict__ winb,
                                             const float* __restrict__ bin,
                                             u16* __restrict__ Qg,
                                             u16* __restrict__ Kg,
                                             u16* __restrict__ Vtg) {
  __shared__ u16 Ash[128 * 32];
  __shared__ u16 Bsh[128 * 32];
  f32x4 acc[4][4];
  const int mbase = blockIdx.y * 128, nbase = blockIdx.x * 128;
  gemm_bt_core(xb, winb, EMB, mbase, nbase, Ash, Bsh, acc);
  const int lane = threadIdx.x & 63;
  const int wid = threadIdx.x >> 6;
  const int wr = wid >> 1, wc = wid & 1;
#pragma unroll
  for (int ni = 0; ni < 4; ++ni) {
    const int n = nbase + wc * 64 + ni * 16 + (lane & 15);
    const float bv = bin[n];
    const int part = n >> 10;  // 0=Q 1=K 2=V
    const int e = n & 1023;
    const int h = e >> 6, d = e & 63;
#pragma unroll
    for (int mi = 0; mi < 4; ++mi) {
      const int m0 = mbase + wr * 64 + mi * 16 + (lane >> 4) * 4;
      const int b = m0 >> 10, np = m0 & 1023;  // m0 % 4 == 0 -> all 4 rows same b
      const size_t bh = (size_t)(b * NH + h);
      if (part == 2) {
        uint2 o;
        o.x = (u32)f2bf(acc[mi][ni][0] + bv) | ((u32)f2bf(acc[mi][ni][1] + bv) << 16);
        o.y = (u32)f2bf(acc[mi][ni][2] + bv) | ((u32)f2bf(acc[mi][ni][3] + bv) << 16);
        *reinterpret_cast<uint2*>(Vtg + (bh * HD + d) * NP + np) = o;
      } else {
        u16* dst = (part == 0) ? Qg : Kg;
#pragma unroll
        for (int r = 0; r < 4; ++r)
          dst[(bh * NP + np + r) * HD + d] = f2bf(acc[mi][ni][r] + bv);
      }
    }
  }
}

// ---------------- flash attention with additive bias ----------------
// grid (16 q-tiles, 64 bh). 4 waves x 16 q-rows. KT=64. XOR-swizzled LDS.
// T14 async-STAGE: next tile's K/V global loads issued right after the barrier,
// drained into LDS at the next iteration's top (latency hidden under compute).
__global__ __launch_bounds__(256) void k_attn(const u16* __restrict__ Qg,
                                              const u16* __restrict__ Kg,
                                              const u16* __restrict__ Vtg,
                                              const float* __restrict__ biasg,
                                              u16* __restrict__ aog) {
  __shared__ u16 Ksh[64 * 64];
  __shared__ u16 Vsh[64 * 64];
  __shared__ u16 Pl[4][16 * 64];
  const int tid = threadIdx.x;
  const int lane = tid & 63;
  const int wid = tid >> 6;
  const int bh = blockIdx.y;
  const int qt = blockIdx.x;
  const int q0 = qt * 64 + wid * 16;
  const int lg = lane >> 4;   // 0..3
  const int ll = lane & 15;   // 0..15

  // Q fragments (A-operand), held in registers for the whole kernel
  const u16* qrow = Qg + ((size_t)bh * NP + q0 + ll) * HD + lg * 8;
  const bf16x8 aq0 = *reinterpret_cast<const bf16x8*>(qrow);
  const bf16x8 aq1 = *reinterpret_cast<const bf16x8*>(qrow + 32);

  f32x4 accO[4];
#pragma unroll
  for (int i = 0; i < 4; ++i) accO[i] = zero4();
  float mrun[4], lrun[4];
#pragma unroll
  for (int r = 0; r < 4; ++r) { mrun[r] = -1e30f; lrun[r] = 0.f; }

  const float* biasbase = biasg + ((size_t)bh * NP + q0 + lg * 4) * NP + ll;
  u16* plw = Pl[wid];

  // staging geometry: 256 threads cover 64 rows x 128B (two 32-row halves)
  const int srow = tid >> 3;  // 0..31
  const int sch = tid & 7;    // 0..7
  const u16* kg0 = Kg + ((size_t)bh * NP + srow) * HD + sch * 8;
  const u16* kg1 = Kg + ((size_t)bh * NP + 32 + srow) * HD + sch * 8;
  const u16* vg0 = Vtg + ((size_t)bh * HD + srow) * NP + sch * 8;
  const u16* vg1 = Vtg + ((size_t)bh * HD + 32 + srow) * NP + sch * 8;
  const int soff0 = (srow * 128 + sch * 16) ^ ((srow & 7) << 4);
  const int soff1 = ((srow + 32) * 128 + sch * 16) ^ ((srow & 7) << 4);

  uint4 kr0, kr1, vr0, vr1;
#define LOADKV(kb)                                                     \
  do {                                                                 \
    kr0 = *reinterpret_cast<const uint4*>(kg0 + (size_t)(kb)*HD);      \
    kr1 = *reinterpret_cast<const uint4*>(kg1 + (size_t)(kb)*HD);      \
    vr0 = *reinterpret_cast<const uint4*>(vg0 + (kb));                 \
    vr1 = *reinterpret_cast<const uint4*>(vg1 + (kb));                 \
  } while (0)

  LOADKV(0);

  for (int kt = 0; kt < 16; ++kt) {
    const int kb = kt * 64;
    // drain staged regs into swizzled LDS (implicit vmcnt wait on kr/vr)
    *reinterpret_cast<uint4*>(reinterpret_cast<char*>(Ksh) + soff0) = kr0;
    *reinterpret_cast<uint4*>(reinterpret_cast<char*>(Ksh) + soff1) = kr1;
    *reinterpret_cast<uint4*>(reinterpret_cast<char*>(Vsh) + soff0) = vr0;
    *reinterpret_cast<uint4*>(reinterpret_cast<char*>(Vsh) + soff1) = vr1;
    // bias loads for THIS tile (issued before barrier; consumed after QK^T)
    float bvals[4][4];
#pragma unroll
    for (int cb = 0; cb < 4; ++cb)
#pragma unroll
      for (int r = 0; r < 4; ++r)
        bvals[cb][r] = biasbase[(size_t)r * NP + kb + cb * 16];
    __syncthreads();
    // issue NEXT tile's K/V loads; latency hides under QK^T+softmax+PV
    if (kt < 15) LOADKV(kb + 64);

    // S = Q K^T : per-wave 16q x 64k
    float sv[4][4];
#pragma unroll
    for (int cb = 0; cb < 4; ++cb) {
      const int rk = cb * 16 + ll;
      const int base = rk * 128 + lg * 16;
      const int sw = (rk & 7) << 4;
      bf16x8 bk0 = *reinterpret_cast<const bf16x8*>(
          reinterpret_cast<char*>(Ksh) + (base ^ sw));
      bf16x8 bk1 = *reinterpret_cast<const bf16x8*>(
          reinterpret_cast<char*>(Ksh) + ((base + 64) ^ sw));
      f32x4 a = zero4();
      a = __builtin_amdgcn_mfma_f32_16x16x32_bf16(aq0, bk0, a, 0, 0, 0);
      a = __builtin_amdgcn_mfma_f32_16x16x32_bf16(aq1, bk1, a, 0, 0, 0);
#pragma unroll
      for (int r = 0; r < 4; ++r) sv[cb][r] = a[r] * SCALE + bvals[cb][r];
    }

    // online softmax (rows live on 16-lane groups; reduce with shfl_xor 1/2/4/8)
    float mnew[4], scl[4];
#pragma unroll
    for (int r = 0; r < 4; ++r) {
      float x = fmaxf(fmaxf(sv[0][r], sv[1][r]), fmaxf(sv[2][r], sv[3][r]));
      x = fmaxf(x, __shfl_xor(x, 1));
      x = fmaxf(x, __shfl_xor(x, 2));
      x = fmaxf(x, __shfl_xor(x, 4));
      x = fmaxf(x, __shfl_xor(x, 8));
      mnew[r] = fmaxf(mrun[r], x);
      scl[r] = __expf(mrun[r] - mnew[r]);
      mrun[r] = mnew[r];
    }
#pragma unroll
    for (int cb = 0; cb < 4; ++cb)
#pragma unroll
      for (int r = 0; r < 4; ++r) sv[cb][r] = __expf(sv[cb][r] - mnew[r]);
#pragma unroll
    for (int r = 0; r < 4; ++r) {
      float x = sv[0][r] + sv[1][r] + sv[2][r] + sv[3][r];
      x += __shfl_xor(x, 1);
      x += __shfl_xor(x, 2);
      x += __shfl_xor(x, 4);
      x += __shfl_xor(x, 8);
      lrun[r] = lrun[r] * scl[r] + x;
#pragma unroll
      for (int db = 0; db < 4; ++db) accO[db][r] *= scl[r];
    }
    // P -> per-wave swizzled LDS (transpose for the PV A-operand)
#pragma unroll
    for (int cb = 0; cb < 4; ++cb)
#pragma unroll
      for (int r = 0; r < 4; ++r) {
        const int q = lg * 4 + r;
        const int off = (q * 128 + (cb * 16 + ll) * 2) ^ ((q & 7) << 4);
        *reinterpret_cast<u16*>(reinterpret_cast<char*>(plw) + off) = f2bf(sv[cb][r]);
      }
    // O += P V  (A = P from LDS, B = V^T rows)
#pragma unroll
    for (int ks = 0; ks < 2; ++ks) {
      const int pb = (ll * 128 + ks * 64 + lg * 16) ^ ((ll & 7) << 4);
      bf16x8 ap = *reinterpret_cast<const bf16x8*>(reinterpret_cast<char*>(plw) + pb);
#pragma unroll
      for (int db = 0; db < 4; ++db) {
        const int rd = db * 16 + ll;
        const int vb = (rd * 128 + ks * 64 + lg * 16) ^ ((rd & 7) << 4);
        bf16x8 bv = *reinterpret_cast<const bf16x8*>(reinterpret_cast<char*>(Vsh) + vb);
        accO[db] = __builtin_amdgcn_mfma_f32_16x16x32_bf16(ap, bv, accO[db], 0, 0, 0);
      }
    }
    __syncthreads();
  }
#undef LOADKV

  const int b = bh >> 4, h = bh & 15;
#pragma unroll
  for (int r = 0; r < 4; ++r) {
    const float inv = 1.0f / lrun[r];
    const int q = q0 + lg * 4 + r;
#pragma unroll
    for (int db = 0; db < 4; ++db) {
      const int e = h * HD + db * 16 + ll;
      aog[((size_t)b * NP + q) * EMB + e] = f2bf(accO[db][r] * inv);
    }
  }
}

// ---------------- output projection ----------------
__global__ __launch_bounds__(256) void k_oproj(const u16* __restrict__ aog,
                                               const u16* __restrict__ woutb,
                                               const float* __restrict__ bout,
                                               float* __restrict__ out) {
  __shared__ u16 Ash[128 * 32];
  __shared__ u16 Bsh[128 * 32];
  f32x4 acc[4][4];
  const int mbase = blockIdx.y * 128, nbase = blockIdx.x * 128;
  gemm_bt_core(aog, woutb, EMB, mbase, nbase, Ash, Bsh, acc);
  const int lane = threadIdx.x & 63;
  const int wid = threadIdx.x >> 6;
  const int wr = wid >> 1, wc = wid & 1;
#pragma unroll
  for (int ni = 0; ni < 4; ++ni) {
    const int n = nbase + wc * 64 + ni * 16 + (lane & 15);
    const float bv = bout[n];
#pragma unroll
    for (int mi = 0; mi < 4; ++mi) {
      const int m0 = mbase + wr * 64 + mi * 16 + (lane >> 4) * 4;
#pragma unroll
      for (int r = 0; r < 4; ++r)
        out[(size_t)(m0 + r) * EMB + n] = acc[mi][ni][r] + bv;
    }
  }
}

extern "C" void kernel_launch(void* const* d_in, const int* in_sizes, int n_in,
                              void* d_out, int out_size, void* d_ws, size_t ws_size,
                              hipStream_t stream) {
  const float* x = (const float*)d_in[0];
  const float* attn_bias = (const float*)d_in[1];
  const float* w_in = (const float*)d_in[2];
  const float* b_in = (const float*)d_in[3];
  const float* w_out = (const float*)d_in[4];
  const float* b_out = (const float*)d_in[5];
  float* out = (float*)d_out;

  char* ws = (char*)d_ws;
  // Layout (40 MB total). aog aliases xb: xb is dead after k_qkv, aog is
  // written by k_attn which launches after k_qkv on the same stream.
  u16* xb    = (u16*)(ws + (0u << 20));    // 8 MB  [4096][1024] bf16
  u16* aog   = (u16*)(ws + (0u << 20));    // 8 MB  [4096][1024] bf16 (aliases xb)
  u16* winb  = (u16*)(ws + (8u << 20));    // 6 MB  [3072][1024] bf16
  u16* woutb = (u16*)(ws + (14u << 20));   // 2 MB  [1024][1024] bf16
  u16* Qg    = (u16*)(ws + (16u << 20));   // 8 MB  [64][1024][64] bf16
  u16* Kg    = (u16*)(ws + (24u << 20));   // 8 MB  [64][1024][64] bf16
  u16* Vtg   = (u16*)(ws + (32u << 20));   // 8 MB  [64][64][1024] bf16 (V transposed)

  k_convert3<<<8192, 256, 0, stream>>>(x, w_in, w_out, xb, winb, woutb);
  k_qkv<<<dim3(24, 32), 256, 0, stream>>>(xb, winb, b_in, Qg, Kg, Vtg);
  k_attn<<<dim3(16, 64), 256, 0, stream>>>(Qg, Kg, Vtg, attn_bias, aog);
  k_oproj<<<dim3(8, 32), 256, 0, stream>>>(aog, woutb, b_out, out);
}